// Round 4
// baseline (310.518 us; speedup 1.0000x reference)
//
#include <hip/hip_runtime.h>
#include <hip/hip_bf16.h>

#define DIM 256
#define HEADS 8
#define DHEAD 32
#define SEQ 2048
#define BATCH 2
#define NROWS (BATCH*SEQ)    // 4096 total rows
#define EPS 1e-5f

typedef __attribute__((ext_vector_type(8))) short bf16x8;   // MFMA A/B frag (4 VGPRs)
typedef __attribute__((ext_vector_type(4))) float f32x4;    // MFMA C/D frag

__device__ __forceinline__ unsigned short f2b(float f) {
    __hip_bfloat16 h = __float2bfloat16(f);
    return *reinterpret_cast<unsigned short*>(&h);
}

__device__ __forceinline__ bf16x8 cvt8(float4 a, float4 b) {
    bf16x8 r;
    r[0] = (short)f2b(a.x); r[1] = (short)f2b(a.y);
    r[2] = (short)f2b(a.z); r[3] = (short)f2b(a.w);
    r[4] = (short)f2b(b.x); r[5] = (short)f2b(b.y);
    r[6] = (short)f2b(b.z); r[7] = (short)f2b(b.w);
    return r;
}

// ---------------------------------------------------------------------------
// Kernel 1 (VERBATIM, passed): q/k/v = x @ {Wq,Wk,Wv} -> bf16.
// ---------------------------------------------------------------------------
__global__ void qkv_proj(const float* __restrict__ x,
                         const float* __restrict__ Wq,
                         const float* __restrict__ Wk,
                         const float* __restrict__ Wv,
                         unsigned short* __restrict__ qo,
                         unsigned short* __restrict__ ko,
                         unsigned short* __restrict__ vt) {
    __shared__ float xs[16][DIM];
    const int t  = threadIdx.x;
    const int r0 = blockIdx.x * 16;
    const float* W = (blockIdx.y == 0) ? Wq : (blockIdx.y == 1) ? Wk : Wv;

    for (int idx = t; idx < 16 * DIM; idx += 256) {
        xs[idx >> 8][idx & 255] = x[(size_t)(r0 + (idx >> 8)) * DIM + (idx & 255)];
    }
    __syncthreads();

    float acc[16];
#pragma unroll
    for (int r = 0; r < 16; r++) acc[r] = 0.f;

    for (int kk = 0; kk < DIM; kk++) {
        float w = W[(size_t)kk * DIM + t];
#pragma unroll
        for (int r = 0; r < 16; r++) acc[r] += xs[r][kk] * w;  // xs broadcast
    }

    const float scale = 0.17677669529663687f;  // 1/sqrt(32)
    if (blockIdx.y == 0) {
#pragma unroll
        for (int r = 0; r < 16; r++)
            qo[(size_t)(r0 + r) * DIM + t] = f2b(acc[r] * scale);
    } else if (blockIdx.y == 1) {
#pragma unroll
        for (int r = 0; r < 16; r++)
            ko[(size_t)(r0 + r) * DIM + t] = f2b(acc[r]);
    } else {
#pragma unroll
        for (int r = 0; r < 16; r++) {
            int row = r0 + r;
            int bb  = row >> 11;          // row / 2048
            int key = row & 2047;
            vt[((size_t)(bb * 256 + t)) * SEQ + key] = f2b(acc[r]);
        }
    }
}

// ---------------------------------------------------------------------------
// Kernel 2 (CHANGED this round): MFMA flash attention, no-max softmax,
// + T14 async-stage: K/V tile jt+1 is loaded into REGISTERS during the
//   compute of tile jt; LDS writes happen right after the barrier.
//   Removes the per-iteration vmcnt(0)-at-barrier global-latency drain.
// ---------------------------------------------------------------------------
__global__ __launch_bounds__(256, 2) void attn_mfma(
        const unsigned short* __restrict__ qb,
        const unsigned short* __restrict__ kb,
        const unsigned short* __restrict__ vtb,
        float* __restrict__ attout) {
    __shared__ __align__(16) unsigned short Ks[64][40];      // 64 keys x 32 dims
    __shared__ __align__(16) unsigned short Vs[256][80];     // 256 cols x 64 keys
    __shared__ __align__(16) unsigned short Ps[4][16][72];   // per-wave P tile

    const int t    = threadIdx.x;
    const int w    = t >> 6;
    const int lane = t & 63;
    const int quad = lane >> 4;
    const int c16  = lane & 15;
    const int h    = blockIdx.y;
    const int b    = blockIdx.z;
    const int i0   = blockIdx.x * 64 + w * 16;

    const size_t qk_head = ((size_t)b * SEQ) * DIM + h * DHEAD;

    bf16x8 qf = *(const bf16x8*)&qb[qk_head + (size_t)(i0 + c16) * DIM + quad * 8];

    // staging thread roles (fixed per thread)
    const int kkey  = t >> 2, kpart = t & 3;                 // K: 1 frag/thread
    const unsigned short* ksrc = kb + qk_head + (size_t)kkey * DIM + kpart * 8;
    const size_t vbase = ((size_t)b * 256) * SEQ;            // V: 8 frags/thread

    f32x4 acc[16];
#pragma unroll
    for (int nt = 0; nt < 16; nt++) acc[nt] = (f32x4){0.f, 0.f, 0.f, 0.f};
    float lrow[4] = {0.f, 0.f, 0.f, 0.f};
    const f32x4 zero = (f32x4){0.f, 0.f, 0.f, 0.f};

    // prologue: load tile 0 into registers
    bf16x8 kreg = *(const bf16x8*)(ksrc);
    bf16x8 vreg[8];
#pragma unroll
    for (int i = 0; i < 8; i++) {
        int id = t + i * 256;
        int col = id >> 3, part = id & 7;
        vreg[i] = *(const bf16x8*)&vtb[vbase + (size_t)col * SEQ + part * 8];
    }

    for (int jt = 0; jt < SEQ / 64; jt++) {
        __syncthreads();   // previous tile's LDS reads complete
        // commit registers -> LDS
        *(bf16x8*)&Ks[kkey][kpart * 8] = kreg;
#pragma unroll
        for (int i = 0; i < 8; i++) {
            int id = t + i * 256;
            int col = id >> 3, part = id & 7;
            *(bf16x8*)&Vs[col][part * 8] = vreg[i];
        }
        __syncthreads();   // tile jt visible to all waves

        // issue tile jt+1 global loads; they retire under the compute below
        if (jt + 1 < SEQ / 64) {
            const int j1 = (jt + 1) * 64;
            kreg = *(const bf16x8*)(ksrc + j1);
#pragma unroll
            for (int i = 0; i < 8; i++) {
                int id = t + i * 256;
                int col = id >> 3, part = id & 7;
                vreg[i] = *(const bf16x8*)&vtb[vbase + (size_t)col * SEQ + j1 + part * 8];
            }
        }

        // ---- compute on LDS tile jt ----
        f32x4 s[4];
#pragma unroll
        for (int kt = 0; kt < 4; kt++) {
            bf16x8 kf = *(const bf16x8*)&Ks[kt * 16 + c16][quad * 8];
            s[kt] = __builtin_amdgcn_mfma_f32_16x16x32_bf16(qf, kf, zero, 0, 0, 0);
        }

#pragma unroll
        for (int kt = 0; kt < 4; kt++) {
#pragma unroll
            for (int reg = 0; reg < 4; reg++) {
                float p = __expf(s[kt][reg]);
                lrow[reg] += p;
                Ps[w][quad * 4 + reg][kt * 16 + c16] = f2b(p);
            }
        }
        __builtin_amdgcn_s_waitcnt(0xc07f);  // lgkmcnt(0) only

        bf16x8 pf0 = *(const bf16x8*)&Ps[w][c16][quad * 8];
        bf16x8 pf1 = *(const bf16x8*)&Ps[w][c16][32 + quad * 8];
#pragma unroll
        for (int nt = 0; nt < 16; nt++) {
            bf16x8 vf0 = *(const bf16x8*)&Vs[nt * 16 + c16][quad * 8];
            acc[nt] = __builtin_amdgcn_mfma_f32_16x16x32_bf16(pf0, vf0, acc[nt], 0, 0, 0);
            bf16x8 vf1 = *(const bf16x8*)&Vs[nt * 16 + c16][32 + quad * 8];
            acc[nt] = __builtin_amdgcn_mfma_f32_16x16x32_bf16(pf1, vf1, acc[nt], 0, 0, 0);
        }
    }

#pragma unroll
    for (int reg = 0; reg < 4; reg++) {
        float l = lrow[reg];
#pragma unroll
        for (int m = 1; m <= 8; m <<= 1) l += __shfl_xor(l, m, 64);
        float inv = 1.f / l;
        int row = i0 + quad * 4 + reg;
#pragma unroll
        for (int nt = 0; nt < 16; nt++) {
            attout[((size_t)b * SEQ + row) * (size_t)(HEADS * DIM) + h * DIM + nt * 16 + c16] =
                acc[nt][reg] * inv;
        }
    }
}

// ---------------------------------------------------------------------------
// Kernel 3 (VERBATIM): WoT[n][k] = bf16(Wo[k][n]).  [256][2048]
// ---------------------------------------------------------------------------
__global__ void wprep(const float* __restrict__ Wo,
                      unsigned short* __restrict__ WoT) {
    const int tid = blockIdx.x * 256 + threadIdx.x;
    const int stride = gridDim.x * 256;
    for (int i = tid; i < 256 * 2048; i += stride) {
        int n = i >> 11, k = i & 2047;
        WoT[i] = f2b(Wo[k * 256 + n]);
    }
}

// ---------------------------------------------------------------------------
// Kernel 4 (VERBATIM, passed): MFMA wo + residual + LN1, 1024 threads.
// ---------------------------------------------------------------------------
__global__ __launch_bounds__(1024) void wo_ln_mfma(
        const float* __restrict__ attout,        // [4096][2048] fp32
        const unsigned short* __restrict__ WoT,  // [256][2048] bf16
        const float* __restrict__ x,
        const float* __restrict__ gamma1,
        float* __restrict__ ln1) {
    __shared__ __align__(16) float Cp[4][16][264];   // per-kslice partial C
    __shared__ float ps1[16][16], ps2[16][16];
    __shared__ float mu[16], rsd[16];

    const int t      = threadIdx.x;          // 0..1023
    const int wave   = t >> 6;               // 0..15
    const int kslice = wave >> 2;            // 0..3  -> k0 = kslice*512
    const int wn     = wave & 3;             // col group n0 = wn*64
    const int lane   = t & 63;
    const int quad   = lane >> 4;
    const int c16    = lane & 15;
    const int r0     = blockIdx.x * 16;

    const size_t k0 = (size_t)kslice * 512;
    const float* arow = attout + (size_t)(r0 + c16) * 2048 + k0 + quad * 8;
    const unsigned short* brow = WoT + (size_t)(wn * 64 + c16) * 2048 + k0 + quad * 8;

    f32x4 acc[4];
#pragma unroll
    for (int nt = 0; nt < 4; nt++) acc[nt] = (f32x4){0.f, 0.f, 0.f, 0.f};

    // prime the pipeline (iteration kc=0)
    float4 a0 = *(const float4*)(arow);
    float4 a1 = *(const float4*)(arow + 4);
    bf16x8 bb[4];
#pragma unroll
    for (int nt = 0; nt < 4; nt++) bb[nt] = *(const bf16x8*)(brow + nt * 32768);

    for (int kc = 0; kc < 512; kc += 32) {
        const int kn = (kc + 32 < 512) ? kc + 32 : kc;   // last iter: dummy reload
        float4 na0 = *(const float4*)(arow + kn);
        float4 na1 = *(const float4*)(arow + kn + 4);
        bf16x8 nb[4];
#pragma unroll
        for (int nt = 0; nt < 4; nt++) nb[nt] = *(const bf16x8*)(brow + nt * 32768 + kn);

        bf16x8 afg = cvt8(a0, a1);
#pragma unroll
        for (int nt = 0; nt < 4; nt++)
            acc[nt] = __builtin_amdgcn_mfma_f32_16x16x32_bf16(afg, bb[nt], acc[nt], 0, 0, 0);

        a0 = na0; a1 = na1;
#pragma unroll
        for (int nt = 0; nt < 4; nt++) bb[nt] = nb[nt];
    }

    // stash partial (C/D layout: row=quad*4+reg, col=wn*64+nt*16+c16)
#pragma unroll
    for (int reg = 0; reg < 4; reg++) {
        const int row = quad * 4 + reg;
#pragma unroll
        for (int nt = 0; nt < 4; nt++)
            Cp[kslice][row][wn * 64 + nt * 16 + c16] = acc[nt][reg];
    }
    __syncthreads();

    // reduce 4 k-slices + residual -> Cp[0]
#pragma unroll
    for (int p = 0; p < 4; p++) {
        const int idx = t + p * 1024;
        const int row = idx >> 8, col = idx & 255;
        float v = Cp[0][row][col] + Cp[1][row][col] + Cp[2][row][col] + Cp[3][row][col]
                + x[(size_t)(r0 + row) * 256 + col];
        Cp[0][row][col] = v;
    }
    __syncthreads();

    // LN1 stats: 2-stage row reduction over Cp[0][16][256]
    if (t < 256) {
        const int row = t >> 4, seg = t & 15;
        float s = 0.f, s2 = 0.f;
#pragma unroll
        for (int j = 0; j < 16; j++) { float v = Cp[0][row][seg * 16 + j]; s += v; s2 += v * v; }
        ps1[row][seg] = s; ps2[row][seg] = s2;
    }
    __syncthreads();
    if (t < 16) {
        float s = 0.f, s2 = 0.f;
#pragma unroll
        for (int j = 0; j < 16; j++) { s += ps1[t][j]; s2 += ps2[t][j]; }
        float m = s * (1.0f / 256.0f);
        float var = s2 * (1.0f / 256.0f) - m * m;
        mu[t] = m; rsd[t] = rsqrtf(var + EPS);
    }
    __syncthreads();

    {
        const int row = t >> 6;
        const int c4  = (t & 63) * 4;
        float4 cv = *(const float4*)&Cp[0][row][c4];
        float4 g4 = *(const float4*)&gamma1[c4];
        const float m = mu[row], rd = rsd[row];
        float4 o;
        o.x = (cv.x - m) * rd * g4.x;
        o.y = (cv.y - m) * rd * g4.y;
        o.z = (cv.z - m) * rd * g4.z;
        o.w = (cv.w - m) * rd * g4.w;
        *(float4*)&ln1[(size_t)(r0 + row) * 256 + c4] = o;
    }
}

// ---------------------------------------------------------------------------
// Kernel 5 (REWRITTEN this round): fp32 FFN + LN2, 512 threads + prefetch.
//  - 512 threads, 8 rows/block -> 512 blocks, 2 blocks/CU = 16 waves/CU
//    (4 waves/SIMD, was 2): doubles latency-hiding TLP.
//  - explicit 1-deep register prefetch of the next weight chunk in both
//    GEMM loops (the same fix that took wo_ln_mfma 83.5 -> <20 us).
// ---------------------------------------------------------------------------
__global__ __launch_bounds__(512, 2) void ffn_ln(
        const float* __restrict__ ln1,
        const float* __restrict__ Wf1,
        const float* __restrict__ Wf2,
        const float* __restrict__ gamma2,
        float* __restrict__ out) {
    __shared__ float xs[8][260];   // LN1 rows; reused as C rows for LN2
    __shared__ float hs[8][516];   // relu(x @ Wf1)
    __shared__ float ps1[8][16], ps2[8][16];
    __shared__ float mu[8], rs[8];

    const int t  = threadIdx.x;    // 0..511
    const int r0 = blockIdx.x * 8;

    // load 8 rows x 256 cols as float4 (1 per thread)
    {
        const int row = t >> 6, c4 = (t & 63) << 2;
        *(float4*)&xs[row][c4] = *(const float4*)&ln1[(size_t)(r0 + row) * 256 + c4];
    }
    __syncthreads();

    // ---- FFN1: h[8][512] = relu(xs @ Wf1). thread tile: 2 rows x 4 cols.
    const int rg = t >> 7;           // row group: rows rg*2, rg*2+1
    const int c0 = (t & 127) << 2;   // 4 consecutive cols
    {
        float acc[2][4];
#pragma unroll
        for (int r = 0; r < 2; r++)
#pragma unroll
            for (int c = 0; c < 4; c++) acc[r][c] = 0.f;

        float4 w0 = *(const float4*)&Wf1[(size_t)0 * 512 + c0];
        float4 w1 = *(const float4*)&Wf1[(size_t)1 * 512 + c0];
        float4 w2 = *(const float4*)&Wf1[(size_t)2 * 512 + c0];
        float4 w3 = *(const float4*)&Wf1[(size_t)3 * 512 + c0];

        for (int kk = 0; kk < 256; kk += 4) {
            const int kn = (kk + 4 < 256) ? kk + 4 : kk;
            float4 n0 = *(const float4*)&Wf1[(size_t)(kn + 0) * 512 + c0];
            float4 n1 = *(const float4*)&Wf1[(size_t)(kn + 1) * 512 + c0];
            float4 n2 = *(const float4*)&Wf1[(size_t)(kn + 2) * 512 + c0];
            float4 n3 = *(const float4*)&Wf1[(size_t)(kn + 3) * 512 + c0];
#pragma unroll
            for (int r = 0; r < 2; r++) {
                float4 xv = *(const float4*)&xs[rg * 2 + r][kk];   // broadcast b128
                acc[r][0] += xv.x * w0.x + xv.y * w1.x + xv.z * w2.x + xv.w * w3.x;
                acc[r][1] += xv.x * w0.y + xv.y * w1.y + xv.z * w2.y + xv.w * w3.y;
                acc[r][2] += xv.x * w0.z + xv.y * w1.z + xv.z * w2.z + xv.w * w3.z;
                acc[r][3] += xv.x * w0.w + xv.y * w1.w + xv.z * w2.w + xv.w * w3.w;
            }
            w0 = n0; w1 = n1; w2 = n2; w3 = n3;
        }
#pragma unroll
        for (int r = 0; r < 2; r++) {
            float4 hv;
            hv.x = fmaxf(acc[r][0], 0.f);
            hv.y = fmaxf(acc[r][1], 0.f);
            hv.z = fmaxf(acc[r][2], 0.f);
            hv.w = fmaxf(acc[r][3], 0.f);
            *(float4*)&hs[rg * 2 + r][c0] = hv;
        }
    }
    __syncthreads();

    // ---- FFN2: C[8][256] = hs @ Wf2. thread tile: 2 rows x 2 cols.
    const int c20 = (t & 127) << 1;  // 2 consecutive cols
    {
        float acc[2][2];
#pragma unroll
        for (int r = 0; r < 2; r++) { acc[r][0] = 0.f; acc[r][1] = 0.f; }

        float2 w0 = *(const float2*)&Wf2[(size_t)0 * 256 + c20];
        float2 w1 = *(const float2*)&Wf2[(size_t)1 * 256 + c20];
        float2 w2 = *(const float2*)&Wf2[(size_t)2 * 256 + c20];
        float2 w3 = *(const float2*)&Wf2[(size_t)3 * 256 + c20];

        for (int kk = 0; kk < 512; kk += 4) {
            const int kn = (kk + 4 < 512) ? kk + 4 : kk;
            float2 n0 = *(const float2*)&Wf2[(size_t)(kn + 0) * 256 + c20];
            float2 n1 = *(const float2*)&Wf2[(size_t)(kn + 1) * 256 + c20];
            float2 n2 = *(const float2*)&Wf2[(size_t)(kn + 2) * 256 + c20];
            float2 n3 = *(const float2*)&Wf2[(size_t)(kn + 3) * 256 + c20];
#pragma unroll
            for (int r = 0; r < 2; r++) {
                float4 hv = *(const float4*)&hs[rg * 2 + r][kk];   // broadcast b128
                acc[r][0] += hv.x * w0.x + hv.y * w1.x + hv.z * w2.x + hv.w * w3.x;
                acc[r][1] += hv.x * w0.y + hv.y * w1.y + hv.z * w2.y + hv.w * w3.y;
            }
            w0 = n0; w1 = n1; w2 = n2; w3 = n3;
        }
#pragma unroll
        for (int r = 0; r < 2; r++) {
            float2 cv; cv.x = acc[r][0]; cv.y = acc[r][1];
            *(float2*)&xs[rg * 2 + r][c20] = cv;
        }
    }
    __syncthreads();

    // ---- LN2: 2-stage row reduction over xs[8][256]
    if (t < 128) {
        const int row = t >> 4, seg = t & 15;
        float s = 0.f, s2 = 0.f;
#pragma unroll
        for (int j = 0; j < 16; j++) { float v = xs[row][seg * 16 + j]; s += v; s2 += v * v; }
        ps1[row][seg] = s; ps2[row][seg] = s2;
    }
    __syncthreads();
    if (t < 8) {
        float s = 0.f, s2 = 0.f;
#pragma unroll
        for (int j = 0; j < 16; j++) { s += ps1[t][j]; s2 += ps2[t][j]; }
        float m = s * (1.0f / DIM);
        float var = s2 * (1.0f / DIM) - m * m;
        mu[t] = m;
        rs[t] = rsqrtf(var + EPS);
    }
    __syncthreads();

    // write: 512 threads x float4 = 8 rows x 256 cols
    {
        const int row = t >> 6, c4 = (t & 63) << 2;
        float4 cv = *(const float4*)&xs[row][c4];
        float4 g4 = *(const float4*)&gamma2[c4];
        const float m = mu[row], rd = rs[row];
        float4 o;
        o.x = (cv.x - m) * rd * g4.x;
        o.y = (cv.y - m) * rd * g4.y;
        o.z = (cv.z - m) * rd * g4.z;
        o.w = (cv.w - m) * rd * g4.w;
        *(float4*)&out[(size_t)(r0 + row) * DIM + c4] = o;
    }
}

// ---------------------------------------------------------------------------
extern "C" void kernel_launch(void* const* d_in, const int* in_sizes, int n_in,
                              void* d_out, int out_size, void* d_ws, size_t ws_size,
                              hipStream_t stream) {
    const float* x      = (const float*)d_in[0];
    const float* Wq     = (const float*)d_in[1];
    const float* Wk     = (const float*)d_in[2];
    const float* Wv     = (const float*)d_in[3];
    const float* Wo     = (const float*)d_in[4];
    const float* Wf1    = (const float*)d_in[5];
    const float* Wf2    = (const float*)d_in[6];
    const float* gamma1 = (const float*)d_in[7];
    const float* gamma2 = (const float*)d_in[8];
    float* out = (float*)d_out;

    // workspace layout: unchanged.
    char* base = (char*)d_ws;
    unsigned short* qb  = (unsigned short*)(base);              // 2 MB
    unsigned short* kb  = (unsigned short*)(base +  2097152);   // 2 MB
    unsigned short* vtb = (unsigned short*)(base +  4194304);   // 2 MB
    float* attout       = (float*)         (base +  6291456);   // 32 MB
    float* ln1          = (float*)         (base + 39845888);   // 4 MB
    unsigned short* WoT = (unsigned short*)(base + 44040192);   // 1 MB -> ends 45088768

    wprep<<<64, 256, 0, stream>>>(Wo, WoT);
    qkv_proj<<<dim3(NROWS / 16, 3), 256, 0, stream>>>(x, Wq, Wk, Wv, qb, kb, vtb);
    attn_mfma<<<dim3(SEQ / 64, HEADS, BATCH), 256, 0, stream>>>(qb, kb, vtb, attout);
    wo_ln_mfma<<<NROWS / 16, 1024, 0, stream>>>(attout, WoT, x, gamma1, ln1);
    ffn_ln<<<NROWS / 8, 512, 0, stream>>>(ln1, Wf1, Wf2, gamma2, out);
}

// Round 5
// 247.952 us; speedup vs baseline: 1.2523x; 1.2523x over previous
//
#include <hip/hip_runtime.h>
#include <hip/hip_bf16.h>

#define DIM 256
#define HEADS 8
#define DHEAD 32
#define SEQ 2048
#define BATCH 2
#define NROWS (BATCH*SEQ)    // 4096 total rows
#define EPS 1e-5f

typedef __attribute__((ext_vector_type(8))) short bf16x8;   // MFMA A/B frag (4 VGPRs)
typedef __attribute__((ext_vector_type(4))) short bf16x4;   // 4 bf16 (8B)
typedef __attribute__((ext_vector_type(4))) float f32x4;    // MFMA C/D frag

__device__ __forceinline__ unsigned short f2b(float f) {
    __hip_bfloat16 h = __float2bfloat16(f);
    return *reinterpret_cast<unsigned short*>(&h);
}

__device__ __forceinline__ bf16x8 cvt8(float4 a, float4 b) {
    bf16x8 r;
    r[0] = (short)f2b(a.x); r[1] = (short)f2b(a.y);
    r[2] = (short)f2b(a.z); r[3] = (short)f2b(a.w);
    r[4] = (short)f2b(b.x); r[5] = (short)f2b(b.y);
    r[6] = (short)f2b(b.z); r[7] = (short)f2b(b.w);
    return r;
}

// ---------------------------------------------------------------------------
// Kernel 1 (VERBATIM, passed): q/k/v = x @ {Wq,Wk,Wv} -> bf16.
// ---------------------------------------------------------------------------
__global__ void qkv_proj(const float* __restrict__ x,
                         const float* __restrict__ Wq,
                         const float* __restrict__ Wk,
                         const float* __restrict__ Wv,
                         unsigned short* __restrict__ qo,
                         unsigned short* __restrict__ ko,
                         unsigned short* __restrict__ vt) {
    __shared__ float xs[16][DIM];
    const int t  = threadIdx.x;
    const int r0 = blockIdx.x * 16;
    const float* W = (blockIdx.y == 0) ? Wq : (blockIdx.y == 1) ? Wk : Wv;

    for (int idx = t; idx < 16 * DIM; idx += 256) {
        xs[idx >> 8][idx & 255] = x[(size_t)(r0 + (idx >> 8)) * DIM + (idx & 255)];
    }
    __syncthreads();

    float acc[16];
#pragma unroll
    for (int r = 0; r < 16; r++) acc[r] = 0.f;

    for (int kk = 0; kk < DIM; kk++) {
        float w = W[(size_t)kk * DIM + t];
#pragma unroll
        for (int r = 0; r < 16; r++) acc[r] += xs[r][kk] * w;  // xs broadcast
    }

    const float scale = 0.17677669529663687f;  // 1/sqrt(32)
    if (blockIdx.y == 0) {
#pragma unroll
        for (int r = 0; r < 16; r++)
            qo[(size_t)(r0 + r) * DIM + t] = f2b(acc[r] * scale);
    } else if (blockIdx.y == 1) {
#pragma unroll
        for (int r = 0; r < 16; r++)
            ko[(size_t)(r0 + r) * DIM + t] = f2b(acc[r]);
    } else {
#pragma unroll
        for (int r = 0; r < 16; r++) {
            int row = r0 + r;
            int bb  = row >> 11;          // row / 2048
            int key = row & 2047;
            vt[((size_t)(bb * 256 + t)) * SEQ + key] = f2b(acc[r]);
        }
    }
}

// ---------------------------------------------------------------------------
// Kernel 2 (VERBATIM, passed): MFMA flash attention, no-max softmax, T14.
// ---------------------------------------------------------------------------
__global__ __launch_bounds__(256, 2) void attn_mfma(
        const unsigned short* __restrict__ qb,
        const unsigned short* __restrict__ kb,
        const unsigned short* __restrict__ vtb,
        float* __restrict__ attout) {
    __shared__ __align__(16) unsigned short Ks[64][40];      // 64 keys x 32 dims
    __shared__ __align__(16) unsigned short Vs[256][80];     // 256 cols x 64 keys
    __shared__ __align__(16) unsigned short Ps[4][16][72];   // per-wave P tile

    const int t    = threadIdx.x;
    const int w    = t >> 6;
    const int lane = t & 63;
    const int quad = lane >> 4;
    const int c16  = lane & 15;
    const int h    = blockIdx.y;
    const int b    = blockIdx.z;
    const int i0   = blockIdx.x * 64 + w * 16;

    const size_t qk_head = ((size_t)b * SEQ) * DIM + h * DHEAD;

    bf16x8 qf = *(const bf16x8*)&qb[qk_head + (size_t)(i0 + c16) * DIM + quad * 8];

    const int kkey  = t >> 2, kpart = t & 3;                 // K: 1 frag/thread
    const unsigned short* ksrc = kb + qk_head + (size_t)kkey * DIM + kpart * 8;
    const size_t vbase = ((size_t)b * 256) * SEQ;            // V: 8 frags/thread

    f32x4 acc[16];
#pragma unroll
    for (int nt = 0; nt < 16; nt++) acc[nt] = (f32x4){0.f, 0.f, 0.f, 0.f};
    float lrow[4] = {0.f, 0.f, 0.f, 0.f};
    const f32x4 zero = (f32x4){0.f, 0.f, 0.f, 0.f};

    bf16x8 kreg = *(const bf16x8*)(ksrc);
    bf16x8 vreg[8];
#pragma unroll
    for (int i = 0; i < 8; i++) {
        int id = t + i * 256;
        int col = id >> 3, part = id & 7;
        vreg[i] = *(const bf16x8*)&vtb[vbase + (size_t)col * SEQ + part * 8];
    }

    for (int jt = 0; jt < SEQ / 64; jt++) {
        __syncthreads();
        *(bf16x8*)&Ks[kkey][kpart * 8] = kreg;
#pragma unroll
        for (int i = 0; i < 8; i++) {
            int id = t + i * 256;
            int col = id >> 3, part = id & 7;
            *(bf16x8*)&Vs[col][part * 8] = vreg[i];
        }
        __syncthreads();

        if (jt + 1 < SEQ / 64) {
            const int j1 = (jt + 1) * 64;
            kreg = *(const bf16x8*)(ksrc + j1);
#pragma unroll
            for (int i = 0; i < 8; i++) {
                int id = t + i * 256;
                int col = id >> 3, part = id & 7;
                vreg[i] = *(const bf16x8*)&vtb[vbase + (size_t)col * SEQ + j1 + part * 8];
            }
        }

        f32x4 s[4];
#pragma unroll
        for (int kt = 0; kt < 4; kt++) {
            bf16x8 kf = *(const bf16x8*)&Ks[kt * 16 + c16][quad * 8];
            s[kt] = __builtin_amdgcn_mfma_f32_16x16x32_bf16(qf, kf, zero, 0, 0, 0);
        }

#pragma unroll
        for (int kt = 0; kt < 4; kt++) {
#pragma unroll
            for (int reg = 0; reg < 4; reg++) {
                float p = __expf(s[kt][reg]);
                lrow[reg] += p;
                Ps[w][quad * 4 + reg][kt * 16 + c16] = f2b(p);
            }
        }
        __builtin_amdgcn_s_waitcnt(0xc07f);  // lgkmcnt(0) only

        bf16x8 pf0 = *(const bf16x8*)&Ps[w][c16][quad * 8];
        bf16x8 pf1 = *(const bf16x8*)&Ps[w][c16][32 + quad * 8];
#pragma unroll
        for (int nt = 0; nt < 16; nt++) {
            bf16x8 vf0 = *(const bf16x8*)&Vs[nt * 16 + c16][quad * 8];
            acc[nt] = __builtin_amdgcn_mfma_f32_16x16x32_bf16(pf0, vf0, acc[nt], 0, 0, 0);
            bf16x8 vf1 = *(const bf16x8*)&Vs[nt * 16 + c16][32 + quad * 8];
            acc[nt] = __builtin_amdgcn_mfma_f32_16x16x32_bf16(pf1, vf1, acc[nt], 0, 0, 0);
        }
    }

#pragma unroll
    for (int reg = 0; reg < 4; reg++) {
        float l = lrow[reg];
#pragma unroll
        for (int m = 1; m <= 8; m <<= 1) l += __shfl_xor(l, m, 64);
        float inv = 1.f / l;
        int row = i0 + quad * 4 + reg;
#pragma unroll
        for (int nt = 0; nt < 16; nt++) {
            attout[((size_t)b * SEQ + row) * (size_t)(HEADS * DIM) + h * DIM + nt * 16 + c16] =
                acc[nt][reg] * inv;
        }
    }
}

// ---------------------------------------------------------------------------
// Kernel 3 (EXTENDED): bf16 transposed weights.
//  WoT[n][k]  = Wo[k][n]   (n<256,  k<2048)
//  W1T[n][k]  = Wf1[k][n]  (n<512,  k<256)
//  W2T[n][k]  = Wf2[k][n]  (n<256,  k<512)
// ---------------------------------------------------------------------------
__global__ void wprep(const float* __restrict__ Wo,
                      const float* __restrict__ Wf1,
                      const float* __restrict__ Wf2,
                      unsigned short* __restrict__ WoT,
                      unsigned short* __restrict__ W1T,
                      unsigned short* __restrict__ W2T) {
    const int tid = blockIdx.x * 256 + threadIdx.x;
    const int stride = gridDim.x * 256;
    const int N1 = 256 * 2048;            // WoT
    const int N2 = N1 + 512 * 256;        // W1T
    const int N3 = N2 + 256 * 512;        // W2T
    for (int i = tid; i < N3; i += stride) {
        if (i < N1) {
            int n = i >> 11, k = i & 2047;
            WoT[i] = f2b(Wo[k * 256 + n]);
        } else if (i < N2) {
            int j = i - N1;
            int n = j >> 8, k = j & 255;
            W1T[j] = f2b(Wf1[k * 512 + n]);
        } else {
            int j = i - N2;
            int n = j >> 9, k = j & 511;
            W2T[j] = f2b(Wf2[k * 256 + n]);
        }
    }
}

// ---------------------------------------------------------------------------
// Kernel 4 (epilogue CHANGED): MFMA wo + residual + LN1 -> ln1 stored as BF16
// (its only consumer is now the MFMA FFN).  Otherwise verbatim.
// ---------------------------------------------------------------------------
__global__ __launch_bounds__(1024) void wo_ln_mfma(
        const float* __restrict__ attout,        // [4096][2048] fp32
        const unsigned short* __restrict__ WoT,  // [256][2048] bf16
        const float* __restrict__ x,
        const float* __restrict__ gamma1,
        unsigned short* __restrict__ ln1b) {     // [4096][256] bf16
    __shared__ __align__(16) float Cp[4][16][264];   // per-kslice partial C
    __shared__ float ps1[16][16], ps2[16][16];
    __shared__ float mu[16], rsd[16];

    const int t      = threadIdx.x;          // 0..1023
    const int wave   = t >> 6;               // 0..15
    const int kslice = wave >> 2;            // 0..3  -> k0 = kslice*512
    const int wn     = wave & 3;             // col group n0 = wn*64
    const int lane   = t & 63;
    const int quad   = lane >> 4;
    const int c16    = lane & 15;
    const int r0     = blockIdx.x * 16;

    const size_t k0 = (size_t)kslice * 512;
    const float* arow = attout + (size_t)(r0 + c16) * 2048 + k0 + quad * 8;
    const unsigned short* brow = WoT + (size_t)(wn * 64 + c16) * 2048 + k0 + quad * 8;

    f32x4 acc[4];
#pragma unroll
    for (int nt = 0; nt < 4; nt++) acc[nt] = (f32x4){0.f, 0.f, 0.f, 0.f};

    float4 a0 = *(const float4*)(arow);
    float4 a1 = *(const float4*)(arow + 4);
    bf16x8 bb[4];
#pragma unroll
    for (int nt = 0; nt < 4; nt++) bb[nt] = *(const bf16x8*)(brow + nt * 32768);

    for (int kc = 0; kc < 512; kc += 32) {
        const int kn = (kc + 32 < 512) ? kc + 32 : kc;   // last iter: dummy reload
        float4 na0 = *(const float4*)(arow + kn);
        float4 na1 = *(const float4*)(arow + kn + 4);
        bf16x8 nb[4];
#pragma unroll
        for (int nt = 0; nt < 4; nt++) nb[nt] = *(const bf16x8*)(brow + nt * 32768 + kn);

        bf16x8 afg = cvt8(a0, a1);
#pragma unroll
        for (int nt = 0; nt < 4; nt++)
            acc[nt] = __builtin_amdgcn_mfma_f32_16x16x32_bf16(afg, bb[nt], acc[nt], 0, 0, 0);

        a0 = na0; a1 = na1;
#pragma unroll
        for (int nt = 0; nt < 4; nt++) bb[nt] = nb[nt];
    }

#pragma unroll
    for (int reg = 0; reg < 4; reg++) {
        const int row = quad * 4 + reg;
#pragma unroll
        for (int nt = 0; nt < 4; nt++)
            Cp[kslice][row][wn * 64 + nt * 16 + c16] = acc[nt][reg];
    }
    __syncthreads();

#pragma unroll
    for (int p = 0; p < 4; p++) {
        const int idx = t + p * 1024;
        const int row = idx >> 8, col = idx & 255;
        float v = Cp[0][row][col] + Cp[1][row][col] + Cp[2][row][col] + Cp[3][row][col]
                + x[(size_t)(r0 + row) * 256 + col];
        Cp[0][row][col] = v;
    }
    __syncthreads();

    if (t < 256) {
        const int row = t >> 4, seg = t & 15;
        float s = 0.f, s2 = 0.f;
#pragma unroll
        for (int j = 0; j < 16; j++) { float v = Cp[0][row][seg * 16 + j]; s += v; s2 += v * v; }
        ps1[row][seg] = s; ps2[row][seg] = s2;
    }
    __syncthreads();
    if (t < 16) {
        float s = 0.f, s2 = 0.f;
#pragma unroll
        for (int j = 0; j < 16; j++) { s += ps1[t][j]; s2 += ps2[t][j]; }
        float m = s * (1.0f / 256.0f);
        float var = s2 * (1.0f / 256.0f) - m * m;
        mu[t] = m; rsd[t] = rsqrtf(var + EPS);
    }
    __syncthreads();

    {
        const int row = t >> 6;
        const int c4  = (t & 63) * 4;
        float4 cv = *(const float4*)&Cp[0][row][c4];
        float4 g4 = *(const float4*)&gamma1[c4];
        const float m = mu[row], rd = rsd[row];
        bf16x4 o4;
        o4[0] = (short)f2b((cv.x - m) * rd * g4.x);
        o4[1] = (short)f2b((cv.y - m) * rd * g4.y);
        o4[2] = (short)f2b((cv.z - m) * rd * g4.z);
        o4[3] = (short)f2b((cv.w - m) * rd * g4.w);
        *(bf16x4*)&ln1b[(size_t)(r0 + row) * 256 + c4] = o4;
    }
}

// ---------------------------------------------------------------------------
// Kernel 5 (REWRITTEN this round): MFMA bf16 FFN + LN2.
//  16 rows/block, 1024 threads (16 waves) — the proven wo_ln structure.
//  GEMM1 M16/N512/K256: wave w owns cols [w*32, w*32+32), 8 k-steps.
//  GEMM2 M16/N256/K512: wave w owns cols [w*16, w*16+16), 16 k-steps.
//  Weights read exactly once per block (bf16), B-prefetch 1-deep.
// ---------------------------------------------------------------------------
__global__ __launch_bounds__(1024) void ffn_ln(
        const unsigned short* __restrict__ ln1b,  // [4096][256] bf16
        const unsigned short* __restrict__ W1T,   // [512][256] bf16
        const unsigned short* __restrict__ W2T,   // [256][512] bf16
        const float* __restrict__ gamma2,
        float* __restrict__ out) {
    __shared__ __align__(16) unsigned short xsb[16][264];  // A1 (bf16)
    __shared__ __align__(16) unsigned short hsb[16][520];  // relu(h) (bf16)
    __shared__ __align__(16) float Cs[16][264];            // C (fp32)
    __shared__ float ps1[16][16], ps2[16][16];
    __shared__ float mu[16], rsd[16];

    const int t    = threadIdx.x;         // 0..1023
    const int w    = t >> 6;              // wave 0..15
    const int lane = t & 63;
    const int quad = lane >> 4;
    const int c16  = lane & 15;
    const int r0   = blockIdx.x * 16;
    const f32x4 zero = (f32x4){0.f, 0.f, 0.f, 0.f};

    // stage A: 16 rows x 256 cols bf16 (4 shorts/thread)
    {
        const int row = t >> 6, c4 = (t & 63) * 4;
        *(bf16x4*)&xsb[row][c4] = *(const bf16x4*)&ln1b[(size_t)(r0 + row) * 256 + c4];
    }

    // ---- GEMM1: h = relu(A @ Wf1), wave tile 16x32 ----
    f32x4 acc1[2];
    acc1[0] = zero; acc1[1] = zero;
    const unsigned short* b1 = W1T + (size_t)(w * 32 + c16) * 256 + quad * 8;
    bf16x8 b10 = *(const bf16x8*)(b1);
    bf16x8 b11 = *(const bf16x8*)(b1 + 16 * 256);
    __syncthreads();   // xsb visible

#pragma unroll
    for (int ks = 0; ks < 8; ks++) {
        const int kn = (ks + 1 < 8) ? (ks + 1) * 32 : ks * 32;
        bf16x8 n0 = *(const bf16x8*)(b1 + kn);
        bf16x8 n1 = *(const bf16x8*)(b1 + 16 * 256 + kn);
        bf16x8 af = *(const bf16x8*)&xsb[c16][ks * 32 + quad * 8];
        acc1[0] = __builtin_amdgcn_mfma_f32_16x16x32_bf16(af, b10, acc1[0], 0, 0, 0);
        acc1[1] = __builtin_amdgcn_mfma_f32_16x16x32_bf16(af, b11, acc1[1], 0, 0, 0);
        b10 = n0; b11 = n1;
    }

    // relu + bf16 -> hsb (C/D layout: row=quad*4+reg, col=w*32+nt*16+c16)
#pragma unroll
    for (int nt = 0; nt < 2; nt++)
#pragma unroll
        for (int reg = 0; reg < 4; reg++)
            hsb[quad * 4 + reg][w * 32 + nt * 16 + c16] =
                f2b(fmaxf(acc1[nt][reg], 0.f));
    __syncthreads();

    // ---- GEMM2: C = h @ Wf2, wave tile 16x16 ----
    f32x4 acc2 = zero;
    const unsigned short* b2 = W2T + (size_t)(w * 16 + c16) * 512 + quad * 8;
    bf16x8 b20 = *(const bf16x8*)(b2);
#pragma unroll
    for (int ks = 0; ks < 16; ks++) {
        const int kn = (ks + 1 < 16) ? (ks + 1) * 32 : ks * 32;
        bf16x8 n0 = *(const bf16x8*)(b2 + kn);
        bf16x8 af = *(const bf16x8*)&hsb[c16][ks * 32 + quad * 8];
        acc2 = __builtin_amdgcn_mfma_f32_16x16x32_bf16(af, b20, acc2, 0, 0, 0);
        b20 = n0;
    }
#pragma unroll
    for (int reg = 0; reg < 4; reg++)
        Cs[quad * 4 + reg][w * 16 + c16] = acc2[reg];
    __syncthreads();

    // ---- LN2: 2-stage row reduction over Cs[16][256] ----
    if (t < 256) {
        const int row = t >> 4, seg = t & 15;
        float s = 0.f, s2 = 0.f;
#pragma unroll
        for (int j = 0; j < 16; j++) { float v = Cs[row][seg * 16 + j]; s += v; s2 += v * v; }
        ps1[row][seg] = s; ps2[row][seg] = s2;
    }
    __syncthreads();
    if (t < 16) {
        float s = 0.f, s2 = 0.f;
#pragma unroll
        for (int j = 0; j < 16; j++) { s += ps1[t][j]; s2 += ps2[t][j]; }
        float m = s * (1.0f / DIM);
        float var = s2 * (1.0f / DIM) - m * m;
        mu[t] = m;
        rsd[t] = rsqrtf(var + EPS);
    }
    __syncthreads();

    // write: 1024 threads x float4 = 16 rows x 256 cols
    {
        const int row = t >> 6, c4 = (t & 63) * 4;
        float4 cv = *(const float4*)&Cs[row][c4];
        float4 g4 = *(const float4*)&gamma2[c4];
        const float m = mu[row], rd = rsd[row];
        float4 o;
        o.x = (cv.x - m) * rd * g4.x;
        o.y = (cv.y - m) * rd * g4.y;
        o.z = (cv.z - m) * rd * g4.z;
        o.w = (cv.w - m) * rd * g4.w;
        *(float4*)&out[(size_t)(r0 + row) * DIM + c4] = o;
    }
}

// ---------------------------------------------------------------------------
extern "C" void kernel_launch(void* const* d_in, const int* in_sizes, int n_in,
                              void* d_out, int out_size, void* d_ws, size_t ws_size,
                              hipStream_t stream) {
    const float* x      = (const float*)d_in[0];
    const float* Wq     = (const float*)d_in[1];
    const float* Wk     = (const float*)d_in[2];
    const float* Wv     = (const float*)d_in[3];
    const float* Wo     = (const float*)d_in[4];
    const float* Wf1    = (const float*)d_in[5];
    const float* Wf2    = (const float*)d_in[6];
    const float* gamma1 = (const float*)d_in[7];
    const float* gamma2 = (const float*)d_in[8];
    float* out = (float*)d_out;

    // workspace layout (ln1 fp32 slot reused for bf16 ln1 + FFN weights)
    char* base = (char*)d_ws;
    unsigned short* qb   = (unsigned short*)(base);              // 2 MB
    unsigned short* kb   = (unsigned short*)(base +  2097152);   // 2 MB
    unsigned short* vtb  = (unsigned short*)(base +  4194304);   // 2 MB
    float* attout        = (float*)         (base +  6291456);   // 32 MB
    unsigned short* ln1b = (unsigned short*)(base + 39845888);   // 2 MB
    unsigned short* W1T  = (unsigned short*)(base + 41943040);   // 256 KB
    unsigned short* W2T  = (unsigned short*)(base + 42205184);   // 256 KB
    unsigned short* WoT  = (unsigned short*)(base + 44040192);   // 1 MB

    wprep<<<64, 256, 0, stream>>>(Wo, Wf1, Wf2, WoT, W1T, W2T);
    qkv_proj<<<dim3(NROWS / 16, 3), 256, 0, stream>>>(x, Wq, Wk, Wv, qb, kb, vtb);
    attn_mfma<<<dim3(SEQ / 64, HEADS, BATCH), 256, 0, stream>>>(qb, kb, vtb, attout);
    wo_ln_mfma<<<NROWS / 16, 1024, 0, stream>>>(attout, WoT, x, gamma1, ln1b);
    ffn_ln<<<NROWS / 16, 1024, 0, stream>>>(ln1b, W1T, W2T, gamma2, out);
}